// Round 1
// baseline (418.115 us; speedup 1.0000x reference)
//
#include <hip/hip_runtime.h>

#define NT   8192   // tokens
#define CIN  4096   // in_channel
#define COUT 4096   // out_channel
#define RK   16     // rank

// ---------------------------------------------------------------------------
// Kernel 1: t[NT][RK] = x @ right^T   (split-k, atomic accumulate)
// grid = 512 blocks (128 row-groups x 4 k-splits), 256 threads (4 waves).
// Each wave: 64 rows x 256 k, in 8 tiles of 32 k staged through a PRIVATE
// LDS region (waves own disjoint k-ranges -> no __syncthreads at all).
// Compute phase: lane = row, k serial -> right[r][k] is wave-uniform -> SGPR.
// ---------------------------------------------------------------------------
__global__ __launch_bounds__(256) void k1_xt(const float* __restrict__ x,
                                             const float* __restrict__ rgt,
                                             float* __restrict__ t)
{
    __shared__ float xs[4][64][33];   // stride 33: read bank=(row+k)%32 -> 2-way=free
    const int bid = blockIdx.x;
    const int rg  = bid >> 2;         // row group 0..127
    const int ks  = bid & 3;          // k split   0..3
    const int tid = threadIdx.x;
    const int l   = tid & 63;         // lane
    const int wv  = __builtin_amdgcn_readfirstlane(tid >> 6);  // wave id (uniform)

    const int row0 = rg * 64;
    const int kw0  = ks * 1024 + wv * 256;

    float acc[RK];
#pragma unroll
    for (int r = 0; r < RK; ++r) acc[r] = 0.f;

    for (int t8 = 0; t8 < 8; ++t8) {
        const int kwin = kw0 + t8 * 32;
        // ---- stage 64 rows x 32 k, coalesced (8 rows x 128B per float4 inst)
#pragma unroll
        for (int i = 0; i < 8; ++i) {
            const int f   = i * 64 + l;
            const int row = f >> 3;
            const int kv  = (f & 7) * 4;
            const float4 v = *(const float4*)&x[(size_t)(row0 + row) * CIN + (kwin + kv)];
            xs[wv][row][kv + 0] = v.x;
            xs[wv][row][kv + 1] = v.y;
            xs[wv][row][kv + 2] = v.z;
            xs[wv][row][kv + 3] = v.w;
        }
        __builtin_amdgcn_wave_barrier();   // same-wave LDS: in-order DS pipe, no s_barrier
        // ---- compute: lane = row; right loads are wave-uniform -> s_load
#pragma unroll
        for (int kk4 = 0; kk4 < 8; ++kk4) {
            float4 rv[RK];
#pragma unroll
            for (int r = 0; r < RK; ++r)
                rv[r] = *(const float4*)&rgt[r * CIN + kwin + kk4 * 4];
            const float x0 = xs[wv][l][kk4 * 4 + 0];
            const float x1 = xs[wv][l][kk4 * 4 + 1];
            const float x2 = xs[wv][l][kk4 * 4 + 2];
            const float x3 = xs[wv][l][kk4 * 4 + 3];
#pragma unroll
            for (int r = 0; r < RK; ++r) {
                acc[r] += rv[r].x * x0;
                acc[r] += rv[r].y * x1;
                acc[r] += rv[r].z * x2;
                acc[r] += rv[r].w * x3;
            }
        }
        __builtin_amdgcn_wave_barrier();
    }

    float* trow = t + (size_t)(row0 + l) * RK;
#pragma unroll
    for (int r = 0; r < RK; ++r) atomicAdd(trow + r, acc[r]);
}

// ---------------------------------------------------------------------------
// Kernel 2: out[NT][COUT] = t @ left^T + bias
// grid = 2048 blocks (4 o-chunks x 512 row-groups of 16 rows), 256 threads.
// Thread owns 4 contiguous o's; left[o][*] lives in 64 VGPRs reused over all
// rows; t[row][*] is wave-uniform -> SGPRs. Stores are coalesced dwordx4.
// ---------------------------------------------------------------------------
__global__ __launch_bounds__(256) void k2_out(const float* __restrict__ t,
                                              const float* __restrict__ lft,
                                              const float* __restrict__ bias,
                                              float* __restrict__ out)
{
    const int bid = blockIdx.x;
    const int oc  = bid & 3;          // o-chunk 0..3
    const int rg  = bid >> 2;         // row group 0..511
    const int tid = threadIdx.x;
    const int o0  = oc * 1024 + tid * 4;

    float4 lf[4][4];                  // left[o0+oo][q*4..q*4+3]
#pragma unroll
    for (int oo = 0; oo < 4; ++oo)
#pragma unroll
        for (int q = 0; q < 4; ++q)
            lf[oo][q] = *(const float4*)&lft[(size_t)(o0 + oo) * RK + q * 4];
    const float4 bv = *(const float4*)&bias[o0];
    const float  bvf[4] = {bv.x, bv.y, bv.z, bv.w};

    const int row0 = rg * 16;
#pragma unroll 2
    for (int rr = 0; rr < 16; ++rr) {
        const int row = row0 + rr;
        float4 ts[4];                 // uniform -> s_load_dwordx4
#pragma unroll
        for (int q = 0; q < 4; ++q)
            ts[q] = *(const float4*)&t[row * RK + q * 4];

        float res[4];
#pragma unroll
        for (int oo = 0; oo < 4; ++oo) {
            float a = bvf[oo];
#pragma unroll
            for (int q = 0; q < 4; ++q) {
                a += lf[oo][q].x * ts[q].x;
                a += lf[oo][q].y * ts[q].y;
                a += lf[oo][q].z * ts[q].z;
                a += lf[oo][q].w * ts[q].w;
            }
            res[oo] = a;
        }
        float4 r4 = make_float4(res[0], res[1], res[2], res[3]);
        *(float4*)&out[(size_t)row * COUT + o0] = r4;
    }
}

extern "C" void kernel_launch(void* const* d_in, const int* in_sizes, int n_in,
                              void* d_out, int out_size, void* d_ws, size_t ws_size,
                              hipStream_t stream)
{
    const float* x    = (const float*)d_in[0];
    const float* lft  = (const float*)d_in[1];   // [COUT][RK]
    const float* rgt  = (const float*)d_in[2];   // [RK][CIN]
    const float* bias = (const float*)d_in[3];
    float*       out  = (float*)d_out;
    float*       t    = (float*)d_ws;            // [NT][RK] scratch, 512 KB

    hipMemsetAsync(t, 0, (size_t)NT * RK * sizeof(float), stream);
    k1_xt<<<dim3(512), dim3(256), 0, stream>>>(x, rgt, t);
    k2_out<<<dim3(2048), dim3(256), 0, stream>>>(t, lft, bias, out);
}

// Round 2
// 291.217 us; speedup vs baseline: 1.4358x; 1.4358x over previous
//
#include <hip/hip_runtime.h>

#define NT   8192   // tokens
#define CIN  4096   // in_channel
#define COUT 4096   // out_channel
#define RK   16     // rank
#define KSPLIT 16                 // block-level k splits
#define KB   (CIN / KSPLIT)       // 256 k per block
#define KW   (KB / 4)             // 64 k per wave
#define KT   16                   // k per staged tile
#define NTILE (KW / KT)           // 4 tiles per wave

// ---------------------------------------------------------------------------
// Kernel 1: part[s][row][r] partial sums of x @ right^T. No atomics.
// grid = 2048 (128 row-groups x 16 k-splits), 256 threads (4 waves).
// Wave-private LDS staging (no intra-loop __syncthreads); lane = row so
// right[r][k] is wave-uniform -> s_load -> scalar pipe. Block-level LDS
// reduce of the 4 waves -> one coalesced float4 partial store per thread.
// LDS = 4*64*17*4 = 17408 B -> 8 blocks/CU.
// ---------------------------------------------------------------------------
__global__ __launch_bounds__(256) void k1_xt(const float* __restrict__ x,
                                             const float* __restrict__ rgt,
                                             float* __restrict__ part)
{
    __shared__ float xs[4][64][17];   // stride 17: read bank=(l+c)%32 -> 2-way = free
    const int bid = blockIdx.x;
    const int rg  = bid >> 4;         // row group 0..127
    const int ks  = bid & 15;         // k split   0..15
    const int tid = threadIdx.x;
    const int l   = tid & 63;
    const int wv  = __builtin_amdgcn_readfirstlane(tid >> 6);

    const int row0 = rg * 64;
    const int k0   = ks * KB + wv * KW;

    float acc[RK];
#pragma unroll
    for (int r = 0; r < RK; ++r) acc[r] = 0.f;

#pragma unroll
    for (int t4 = 0; t4 < NTILE; ++t4) {
        const int kwin = k0 + t4 * KT;
        // ---- stage 64 rows x 16 k (256 float4, 4 per lane), coalesced
#pragma unroll
        for (int i = 0; i < 4; ++i) {
            const int f   = i * 64 + l;
            const int row = f >> 2;
            const int kv  = (f & 3) * 4;
            const float4 v = *(const float4*)&x[(size_t)(row0 + row) * CIN + (kwin + kv)];
            xs[wv][row][kv + 0] = v.x;
            xs[wv][row][kv + 1] = v.y;
            xs[wv][row][kv + 2] = v.z;
            xs[wv][row][kv + 3] = v.w;
        }
        __builtin_amdgcn_wave_barrier();   // same-wave LDS RAW: DS pipe in-order
        // ---- compute: lane = row; right loads wave-uniform -> s_load_dwordx4
#pragma unroll
        for (int kk4 = 0; kk4 < 4; ++kk4) {
            float4 rv[RK];
#pragma unroll
            for (int r = 0; r < RK; ++r)
                rv[r] = *(const float4*)&rgt[r * CIN + kwin + kk4 * 4];
            const float x0 = xs[wv][l][kk4 * 4 + 0];
            const float x1 = xs[wv][l][kk4 * 4 + 1];
            const float x2 = xs[wv][l][kk4 * 4 + 2];
            const float x3 = xs[wv][l][kk4 * 4 + 3];
#pragma unroll
            for (int r = 0; r < RK; ++r) {
                acc[r] += rv[r].x * x0;
                acc[r] += rv[r].y * x1;
                acc[r] += rv[r].z * x2;
                acc[r] += rv[r].w * x3;
            }
        }
        __builtin_amdgcn_wave_barrier();
    }

    // ---- block-level reduce: each wave parks acc in its own LDS region
    float* red = &xs[wv][0][0];       // 64*17 floats, wave-private
#pragma unroll
    for (int r = 0; r < RK; ++r) red[l * 17 + r] = acc[r];
    __syncthreads();

    // thread t sums 4 (row, r) cells over the 4 waves; coalesced float4 store
    const int row = tid >> 2;         // 0..63
    const int rq  = (tid & 3) * 4;    // 0,4,8,12
    float4 s = make_float4(0.f, 0.f, 0.f, 0.f);
#pragma unroll
    for (int w = 0; w < 4; ++w) {
        const float* rw = &xs[w][0][0];
        s.x += rw[row * 17 + rq + 0];
        s.y += rw[row * 17 + rq + 1];
        s.z += rw[row * 17 + rq + 2];
        s.w += rw[row * 17 + rq + 3];
    }
    *(float4*)&part[((size_t)ks * NT + (row0 + row)) * RK + rq] = s;
}

// ---------------------------------------------------------------------------
// Kernel 1b: t = sum over 16 partial planes. 128 blocks x 256 thr,
// float4 per thread, fully coalesced. ~8.5 MB traffic.
// ---------------------------------------------------------------------------
__global__ __launch_bounds__(256) void k1b_red(const float* __restrict__ part,
                                               float* __restrict__ t)
{
    const int flat = blockIdx.x * 256 + threadIdx.x;   // 0..32767 float4s
    float4 s = make_float4(0.f, 0.f, 0.f, 0.f);
#pragma unroll
    for (int p = 0; p < KSPLIT; ++p) {
        const float4 v = ((const float4*)part)[(size_t)p * (NT * RK / 4) + flat];
        s.x += v.x; s.y += v.y; s.z += v.z; s.w += v.w;
    }
    ((float4*)t)[flat] = s;
}

// ---------------------------------------------------------------------------
// Kernel 2: out = t @ left^T + bias. grid = 2048 (512 row-groups x 4 o-chunks).
// Block's 16 t-rows (1 KB) staged in LDS once -> per-row reads are broadcast
// ds_read_b128 (no global latency in the row loop). left[o][*] in 64 VGPRs
// reused over 16 rows; coalesced dwordx4 stores.
// ---------------------------------------------------------------------------
__global__ __launch_bounds__(256) void k2_out(const float* __restrict__ t,
                                              const float* __restrict__ lft,
                                              const float* __restrict__ bias,
                                              float* __restrict__ out)
{
    __shared__ float tl[16 * RK];     // 1 KB
    const int bid = blockIdx.x;
    const int oc  = bid & 3;
    const int rg  = bid >> 2;         // 0..511
    const int tid = threadIdx.x;
    const int o0  = oc * 1024 + tid * 4;
    const int row0 = rg * 16;

    tl[tid] = t[row0 * RK + tid];     // 256 floats, coalesced

    float4 lf[4][4];
#pragma unroll
    for (int oo = 0; oo < 4; ++oo)
#pragma unroll
        for (int q = 0; q < 4; ++q)
            lf[oo][q] = *(const float4*)&lft[(size_t)(o0 + oo) * RK + q * 4];
    const float4 bv = *(const float4*)&bias[o0];
    const float  bvf[4] = {bv.x, bv.y, bv.z, bv.w};

    __syncthreads();

#pragma unroll 4
    for (int rr = 0; rr < 16; ++rr) {
        float4 ts[4];
#pragma unroll
        for (int q = 0; q < 4; ++q)
            ts[q] = ((const float4*)tl)[rr * 4 + q];   // uniform -> broadcast

        float res[4];
#pragma unroll
        for (int oo = 0; oo < 4; ++oo) {
            float a = bvf[oo];
#pragma unroll
            for (int q = 0; q < 4; ++q) {
                a += lf[oo][q].x * ts[q].x;
                a += lf[oo][q].y * ts[q].y;
                a += lf[oo][q].z * ts[q].z;
                a += lf[oo][q].w * ts[q].w;
            }
            res[oo] = a;
        }
        *(float4*)&out[(size_t)(row0 + rr) * COUT + o0] =
            make_float4(res[0], res[1], res[2], res[3]);
    }
}

extern "C" void kernel_launch(void* const* d_in, const int* in_sizes, int n_in,
                              void* d_out, int out_size, void* d_ws, size_t ws_size,
                              hipStream_t stream)
{
    const float* x    = (const float*)d_in[0];
    const float* lft  = (const float*)d_in[1];   // [COUT][RK]
    const float* rgt  = (const float*)d_in[2];   // [RK][CIN]
    const float* bias = (const float*)d_in[3];
    float*       out  = (float*)d_out;

    float* part = (float*)d_ws;                         // [KSPLIT][NT][RK] = 8 MB
    float* t    = part + (size_t)KSPLIT * NT * RK;      // [NT][RK] = 512 KB

    k1_xt  <<<dim3(2048), dim3(256), 0, stream>>>(x, rgt, part);
    k1b_red<<<dim3(128),  dim3(256), 0, stream>>>(part, t);
    k2_out <<<dim3(2048), dim3(256), 0, stream>>>(t, lft, bias, out);
}

// Round 3
// 285.649 us; speedup vs baseline: 1.4637x; 1.0195x over previous
//
#include <hip/hip_runtime.h>

#define NT   8192   // tokens
#define CIN  4096   // in_channel
#define COUT 4096   // out_channel
#define RK   16     // rank
#define KSPLIT 16                 // k splits (partial planes)
#define KB   (CIN / KSPLIT)       // 256 k per block
#define TK   64                   // k per staged tile
#define NTILE (KB / TK)           // 4 tiles per block
#define XS_STRIDE 65              // row stride in floats: bank=(l+k)%32 -> 2-way = free

// ---------------------------------------------------------------------------
// Kernel 1: part[s][row][r] = partial x @ right^T. Block-cooperative tiles,
// register prefetch: next tile's 16 KB is in flight during current compute.
// grid = 2048 (128 row-groups x 16 k-splits), 256 threads.
// Tile = 64 rows x 64 k. Waves split k 4-ways; lane = row so right[r][k] is
// wave-uniform -> s_load (scalar pipe, no VMEM contention).
// LDS = max(64*65, 4*64*17) floats = 17408 B -> 9 blocks/CU.
// ---------------------------------------------------------------------------
__global__ __launch_bounds__(256) void k1_xt(const float* __restrict__ x,
                                             const float* __restrict__ rgt,
                                             float* __restrict__ part)
{
    __shared__ float lds[4352];       // union: xs[64][65] | red[4][64][17]
    const int bid = blockIdx.x;
    const int rg  = bid >> 4;         // row group 0..127
    const int ks  = bid & 15;         // k split   0..15
    const int tid = threadIdx.x;
    const int l   = tid & 63;
    const int wv  = __builtin_amdgcn_readfirstlane(tid >> 6);

    const int row0 = rg * 64;
    const int kblk = ks * KB;
    // staging coords: thread t step i covers row i*16+(t>>4), k-chunk (t&15)*4
    const int srow = tid >> 4;        // 0..15
    const int skc  = (tid & 15) * 4;  // 0,4,...,60

    float acc[RK];
#pragma unroll
    for (int r = 0; r < RK; ++r) acc[r] = 0.f;

    float4 pf[4];
    const float* xbase = x + (size_t)row0 * CIN + kblk;

    // prefetch tile 0
#pragma unroll
    for (int i = 0; i < 4; ++i)
        pf[i] = *(const float4*)&xbase[(size_t)(i * 16 + srow) * CIN + skc];

    for (int t4 = 0; t4 < NTILE; ++t4) {
        // park prefetched tile in LDS (waits vmcnt for these 4 only)
#pragma unroll
        for (int i = 0; i < 4; ++i) {
            float* p = &lds[(i * 16 + srow) * XS_STRIDE + skc];
            p[0] = pf[i].x; p[1] = pf[i].y; p[2] = pf[i].z; p[3] = pf[i].w;
        }
        // issue next tile's loads NOW -> in flight during compute below
        if (t4 + 1 < NTILE) {
#pragma unroll
            for (int i = 0; i < 4; ++i)
                pf[i] = *(const float4*)&xbase[(size_t)(i * 16 + srow) * CIN
                                               + (t4 + 1) * TK + skc];
        }
        __syncthreads();

        // compute: lane = row, wave's k-quarter = [wv*16, wv*16+16)
        const int kq = t4 * TK + wv * 16;          // offset within block k-range
#pragma unroll
        for (int kk4 = 0; kk4 < 4; ++kk4) {
            float4 rv[RK];
#pragma unroll
            for (int r = 0; r < RK; ++r)           // uniform -> s_load_dwordx4
                rv[r] = *(const float4*)&rgt[r * CIN + kblk + kq + kk4 * 4];
            const int kx = wv * 16 + kk4 * 4;
            const float x0 = lds[l * XS_STRIDE + kx + 0];
            const float x1 = lds[l * XS_STRIDE + kx + 1];
            const float x2 = lds[l * XS_STRIDE + kx + 2];
            const float x3 = lds[l * XS_STRIDE + kx + 3];
#pragma unroll
            for (int r = 0; r < RK; ++r) {
                acc[r] += rv[r].x * x0;
                acc[r] += rv[r].y * x1;
                acc[r] += rv[r].z * x2;
                acc[r] += rv[r].w * x3;
            }
        }
        __syncthreads();   // tile fully consumed before next park
    }

    // ---- block reduce across the 4 waves' k-quarters (stride 17: 2-way = free)
#pragma unroll
    for (int r = 0; r < RK; ++r) lds[(wv * 64 + l) * 17 + r] = acc[r];
    __syncthreads();

    const int row = tid >> 2;         // 0..63
    const int rq  = (tid & 3) * 4;    // 0,4,8,12
    float4 s = make_float4(0.f, 0.f, 0.f, 0.f);
#pragma unroll
    for (int w = 0; w < 4; ++w) {
        const float* rw = &lds[(w * 64 + row) * 17 + rq];
        s.x += rw[0]; s.y += rw[1]; s.z += rw[2]; s.w += rw[3];
    }
    *(float4*)&part[((size_t)ks * NT + (row0 + row)) * RK + rq] = s;
}

// ---------------------------------------------------------------------------
// Kernel 2: out = t @ left^T + bias, with the split-k reduction fused into
// the prologue (16 coalesced loads/thread, mostly L2 hits -> no k1b kernel).
// grid = 2048 (512 row-groups x 4 o-chunks), 256 threads.
// ---------------------------------------------------------------------------
__global__ __launch_bounds__(256) void k2_out(const float* __restrict__ part,
                                              const float* __restrict__ lft,
                                              const float* __restrict__ bias,
                                              float* __restrict__ out)
{
    __shared__ float tl[16 * RK];     // 1 KB: this block's 16 t-rows
    const int bid = blockIdx.x;
    const int oc  = bid & 3;
    const int rg  = bid >> 2;         // 0..511
    const int tid = threadIdx.x;
    const int o0  = oc * 1024 + tid * 4;
    const int row0 = rg * 16;

    // fused split-k reduce: 16 independent coalesced loads, then one LDS write
    float s = 0.f;
#pragma unroll
    for (int p = 0; p < KSPLIT; ++p)
        s += part[((size_t)p * NT + row0) * RK + tid];
    tl[tid] = s;

    float4 lf[4][4];
#pragma unroll
    for (int oo = 0; oo < 4; ++oo)
#pragma unroll
        for (int q = 0; q < 4; ++q)
            lf[oo][q] = *(const float4*)&lft[(size_t)(o0 + oo) * RK + q * 4];
    const float4 bv = *(const float4*)&bias[o0];
    const float  bvf[4] = {bv.x, bv.y, bv.z, bv.w};

    __syncthreads();

#pragma unroll 4
    for (int rr = 0; rr < 16; ++rr) {
        float4 ts[4];
#pragma unroll
        for (int q = 0; q < 4; ++q)
            ts[q] = ((const float4*)tl)[rr * 4 + q];   // uniform -> broadcast

        float res[4];
#pragma unroll
        for (int oo = 0; oo < 4; ++oo) {
            float a = bvf[oo];
#pragma unroll
            for (int q = 0; q < 4; ++q) {
                a += lf[oo][q].x * ts[q].x;
                a += lf[oo][q].y * ts[q].y;
                a += lf[oo][q].z * ts[q].z;
                a += lf[oo][q].w * ts[q].w;
            }
            res[oo] = a;
        }
        *(float4*)&out[(size_t)(row0 + rr) * COUT + o0] =
            make_float4(res[0], res[1], res[2], res[3]);
    }
}

extern "C" void kernel_launch(void* const* d_in, const int* in_sizes, int n_in,
                              void* d_out, int out_size, void* d_ws, size_t ws_size,
                              hipStream_t stream)
{
    const float* x    = (const float*)d_in[0];
    const float* lft  = (const float*)d_in[1];   // [COUT][RK]
    const float* rgt  = (const float*)d_in[2];   // [RK][CIN]
    const float* bias = (const float*)d_in[3];
    float*       out  = (float*)d_out;

    float* part = (float*)d_ws;                  // [KSPLIT][NT][RK] = 8 MB

    k1_xt <<<dim3(2048), dim3(256), 0, stream>>>(x, rgt, part);
    k2_out<<<dim3(2048), dim3(256), 0, stream>>>(part, lft, bias, out);
}